// Round 3
// baseline (226.949 us; speedup 1.0000x reference)
//
#include <hip/hip_runtime.h>
#include <math.h>

// DotProductAttention B=32, L=2048, D=64, fp32 IO, per-batch key-length mask.
// Round 3: bf16 MFMA flash-attention + 2-phase register prefetch pipeline.
//  - 4 waves/block, Q-tile=64 (16 q-rows/wave), K-tile=64.
//  - Prefetch next K/V tile global->regs during compute (T3-minimum / T14):
//    sync; regs->LDS; sync; issue loads(t+1); compute(t).
//  - Vt swizzle fixed: slot = (d ^ (d>>2)) & 7 (old (d&7) collapsed to 2
//    values on the stride-4 write pattern -> 8-way conflict, 1.55e7 counts).
//  - Masked keys -> s=-1e30 -> exp underflows to 0 (== ref's -1e6 fill);
//    mask branch only taken on the final partial tile (block-uniform).

#define BB 32
#define LL 2048
#define DD 64
#define QBLK 64
#define KBLK 64

typedef __attribute__((ext_vector_type(8))) short bf16x8;
typedef __attribute__((ext_vector_type(4))) float f32x4;

static __device__ __forceinline__ short f2bf(float f) {
    union { float f; unsigned u; } v; v.f = f;
    unsigned r = (v.u + 0x7FFFu + ((v.u >> 16) & 1u)) >> 16;
    return (short)r;
}
static __device__ __forceinline__ int kswz(int row) { return (row & 7) << 3; }
static __device__ __forceinline__ int vswz(int d)   { return ((d ^ (d >> 2)) & 7) << 3; }

__global__ __launch_bounds__(256, 4) void attn_mfma_kernel(
    const float* __restrict__ Q, const float* __restrict__ K,
    const float* __restrict__ V, const int* __restrict__ vlen,
    float* __restrict__ O)
{
    __shared__ __align__(16) short Ks[KBLK * DD];      // [k][d], kswz
    __shared__ __align__(16) short Vt[DD * KBLK];      // [d][k], vswz
    __shared__ __align__(16) short Pl[4 * 16 * KBLK];  // per-wave [q][k], kswz

    const int tid  = threadIdx.x;
    const int wid  = tid >> 6;
    const int lane = tid & 63;
    const int lq   = lane & 15;
    const int lg   = lane >> 4;

    const int nqt = LL / QBLK;            // 32
    const int b   = blockIdx.x / nqt;
    const int qt  = blockIdx.x % nqt;
    const int qbase = qt * QBLK + wid * 16;
    const int valid = vlen[b];

    // ---- Q A-fragments in regs: lane holds Q[qbase+lq][ds*32 + lg*8 .. +7]
    bf16x8 qf[2];
    {
        const float* Qr = Q + ((size_t)b * LL + qbase + lq) * DD;
        #pragma unroll
        for (int ds_ = 0; ds_ < 2; ++ds_) {
            const float4* p4 = reinterpret_cast<const float4*>(Qr + ds_ * 32 + lg * 8);
            float4 a = p4[0], c = p4[1];
            bf16x8 f;
            f[0] = f2bf(a.x); f[1] = f2bf(a.y); f[2] = f2bf(a.z); f[3] = f2bf(a.w);
            f[4] = f2bf(c.x); f[5] = f2bf(c.y); f[6] = f2bf(c.z); f[7] = f2bf(c.w);
            qf[ds_] = f;
        }
    }

    f32x4 acc[4];
    #pragma unroll
    for (int n = 0; n < 4; ++n) acc[n] = (f32x4){0.f, 0.f, 0.f, 0.f};
    float m_[4], l_[4];
    #pragma unroll
    for (int r = 0; r < 4; ++r) { m_[r] = -1e30f; l_[r] = 0.f; }

    const int ntiles = (valid + KBLK - 1) / KBLK;
    const float4* Kg4 = reinterpret_cast<const float4*>(K + (size_t)b * LL * DD);
    const float4* Vg4 = reinterpret_cast<const float4*>(V + (size_t)b * LL * DD);

    // ---- prefetch tile 0 into regs
    float4 kpre[4], vpre[4];
    {
        const int base4 = 0;
        #pragma unroll
        for (int i = 0; i < 4; ++i) {
            int idx = tid + i * 256;
            kpre[i] = Kg4[base4 + idx];
            vpre[i] = Vg4[base4 + idx];
        }
    }

    for (int kt = 0; kt < ntiles; ++kt) {
        __syncthreads();   // previous tile's LDS consumers done (drains vmcnt too)

        // ---- write staged regs -> LDS (fp32->bf16, swizzled)
        #pragma unroll
        for (int i = 0; i < 4; ++i) {
            int idx = tid + i * 256;
            int kr  = idx >> 4;
            int dc  = (idx & 15) * 4;
            float4 kv = kpre[i];
            unsigned lo = (unsigned short)f2bf(kv.x) | ((unsigned)(unsigned short)f2bf(kv.y) << 16);
            unsigned hi = (unsigned short)f2bf(kv.z) | ((unsigned)(unsigned short)f2bf(kv.w) << 16);
            int e = (kr * 64 + dc) ^ kswz(kr);
            *reinterpret_cast<unsigned*>(&Ks[e])     = lo;
            *reinterpret_cast<unsigned*>(&Ks[e + 2]) = hi;
            float4 vv = vpre[i];
            Vt[((dc + 0) * 64 + kr) ^ vswz(dc + 0)] = f2bf(vv.x);
            Vt[((dc + 1) * 64 + kr) ^ vswz(dc + 1)] = f2bf(vv.y);
            Vt[((dc + 2) * 64 + kr) ^ vswz(dc + 2)] = f2bf(vv.z);
            Vt[((dc + 3) * 64 + kr) ^ vswz(dc + 3)] = f2bf(vv.w);
        }
        __syncthreads();

        // ---- issue next tile's loads; latency hides under compute below
        if (kt + 1 < ntiles) {
            const int base4 = (kt + 1) * KBLK * (DD / 4);
            #pragma unroll
            for (int i = 0; i < 4; ++i) {
                int idx = tid + i * 256;
                kpre[i] = Kg4[base4 + idx];
                vpre[i] = Vg4[base4 + idx];
            }
        }

        // ---- QK^T
        f32x4 s[4];
        #pragma unroll
        for (int t = 0; t < 4; ++t) {
            f32x4 a = (f32x4){0.f, 0.f, 0.f, 0.f};
            const int krow = t * 16 + lq;
            #pragma unroll
            for (int ds_ = 0; ds_ < 2; ++ds_) {
                int e = (krow * 64 + ds_ * 32 + lg * 8) ^ kswz(krow);
                bf16x8 kf = *reinterpret_cast<const bf16x8*>(&Ks[e]);
                a = __builtin_amdgcn_mfma_f32_16x16x32_bf16(qf[ds_], kf, a, 0, 0, 0);
            }
            s[t] = a;
        }

        // ---- mask(last tile only) + scale + online softmax
        const bool tail = (kt == ntiles - 1) && (valid & (KBLK - 1));
        float rowmax[4];
        #pragma unroll
        for (int r = 0; r < 4; ++r) {
            float mx = -1e30f;
            #pragma unroll
            for (int t = 0; t < 4; ++t) {
                float v = s[t][r] * 0.125f;
                if (tail) {
                    int kg = kt * KBLK + t * 16 + lq;
                    v = (kg < valid) ? v : -1e30f;
                }
                s[t][r] = v;
                mx = fmaxf(mx, v);
            }
            #pragma unroll
            for (int off = 1; off < 16; off <<= 1)
                mx = fmaxf(mx, __shfl_xor(mx, off, 64));
            rowmax[r] = mx;
        }
        float corr[4];
        #pragma unroll
        for (int r = 0; r < 4; ++r) {
            float mnew = fmaxf(m_[r], rowmax[r]);
            corr[r] = __expf(m_[r] - mnew);
            m_[r] = mnew;
            l_[r] *= corr[r];
        }
        #pragma unroll
        for (int n = 0; n < 4; ++n) {
            acc[n][0] *= corr[0]; acc[n][1] *= corr[1];
            acc[n][2] *= corr[2]; acc[n][3] *= corr[3];
        }
        #pragma unroll
        for (int r = 0; r < 4; ++r) {
            float ls = 0.f;
            #pragma unroll
            for (int t = 0; t < 4; ++t) {
                float p = __expf(s[t][r] - m_[r]);
                s[t][r] = p;
                ls += p;
            }
            #pragma unroll
            for (int off = 1; off < 16; off <<= 1)
                ls += __shfl_xor(ls, off, 64);
            l_[r] += ls;
        }

        // ---- P -> wave-private LDS (bf16, kswz)
        short* Pw = &Pl[wid * (16 * KBLK)];
        #pragma unroll
        for (int t = 0; t < 4; ++t) {
            #pragma unroll
            for (int r = 0; r < 4; ++r) {
                int qrow = lg * 4 + r;
                Pw[(qrow * 64 + t * 16 + lq) ^ kswz(qrow)] = f2bf(s[t][r]);
            }
        }

        // ---- PV
        #pragma unroll
        for (int ks_ = 0; ks_ < 2; ++ks_) {
            int pe = (lq * 64 + ks_ * 32 + lg * 8) ^ kswz(lq);
            bf16x8 pf = *reinterpret_cast<const bf16x8*>(&Pw[pe]);
            #pragma unroll
            for (int n = 0; n < 4; ++n) {
                int drow = n * 16 + lq;
                int ve = (drow * 64 + ks_ * 32 + lg * 8) ^ vswz(drow);
                bf16x8 vf = *reinterpret_cast<const bf16x8*>(&Vt[ve]);
                acc[n] = __builtin_amdgcn_mfma_f32_16x16x32_bf16(pf, vf, acc[n], 0, 0, 0);
            }
        }
    }

    // ---- epilogue
    float inv[4];
    #pragma unroll
    for (int r = 0; r < 4; ++r) inv[r] = 1.f / l_[r];
    float* Ob = O + ((size_t)b * LL + qbase) * DD;
    #pragma unroll
    for (int n = 0; n < 4; ++n) {
        #pragma unroll
        for (int r = 0; r < 4; ++r) {
            Ob[(size_t)(lg * 4 + r) * DD + n * 16 + lq] = acc[n][r] * inv[r];
        }
    }
}

extern "C" void kernel_launch(void* const* d_in, const int* in_sizes, int n_in,
                              void* d_out, int out_size, void* d_ws, size_t ws_size,
                              hipStream_t stream) {
    const float* Q = (const float*)d_in[0];
    const float* K = (const float*)d_in[1];
    const float* V = (const float*)d_in[2];
    const int* vlen = (const int*)d_in[3];
    float* O = (float*)d_out;

    dim3 grid(BB * (LL / QBLK));   // 1024 blocks
    dim3 block(256);               // 4 waves
    attn_mfma_kernel<<<grid, block, 0, stream>>>(Q, K, V, vlen, O);
}

// Round 4
// 128.232 us; speedup vs baseline: 1.7698x; 1.7698x over previous
//
#include <hip/hip_runtime.h>
#include <hip/hip_bf16.h>
#include <math.h>

// DotProductAttention B=32, L=2048, D=64, fp32 IO, per-batch key-length mask.
// Round 4: bf16 MFMA flash-attention, 2-phase register prefetch (un-spilled).
//  - launch_bounds(256,2): round-3's (256,4) capped VGPR at 64 -> prefetch
//    regs spilled (WRITE_SIZE 16->47MB). Cap 256 fixes it.
//  - qt-major block mapping: each CU mixes ~4 batches -> load balance across
//    variable valid_len (batch-major gave worst-CU = 2x mean work).
//  - Softmax in exp2 domain: Q pre-scaled by 0.125*log2e, p = exp2(s - m).
//  - Hardware bf16 cvt (__float2bfloat16) instead of manual RNE bit-ops.
//  - Defer-max (T13, THR=8 in log2 domain): skip acc rescale when max
//    growth is small; p <= 2^8, fp32 l/acc headroom is ample.

#define BB 32
#define LL 2048
#define DD 64
#define QBLK 64
#define KBLK 64

typedef __attribute__((ext_vector_type(8))) short bf16x8;
typedef __attribute__((ext_vector_type(4))) float f32x4;

static __device__ __forceinline__ short f2bf(float f) {
    __hip_bfloat16 h = __float2bfloat16(f);
    return *reinterpret_cast<short*>(&h);
}
static __device__ __forceinline__ float exp2c(float x) {
    return __builtin_amdgcn_exp2f(x);
}
static __device__ __forceinline__ int kswz(int row) { return (row & 7) << 3; }
static __device__ __forceinline__ int vswz(int d)   { return ((d ^ (d >> 2)) & 7) << 3; }

__global__ __launch_bounds__(256, 2) void attn_mfma_kernel(
    const float* __restrict__ Q, const float* __restrict__ K,
    const float* __restrict__ V, const int* __restrict__ vlen,
    float* __restrict__ O)
{
    __shared__ __align__(16) short Ks[KBLK * DD];      // [k][d], kswz
    __shared__ __align__(16) short Vt[DD * KBLK];      // [d][k], vswz
    __shared__ __align__(16) short Pl[4 * 16 * KBLK];  // per-wave [q][k], kswz

    const int tid  = threadIdx.x;
    const int wid  = tid >> 6;
    const int lane = tid & 63;
    const int lq   = lane & 15;
    const int lg   = lane >> 4;

    // qt-major: consecutive blocks -> different batches (CU load balance)
    const int b   = blockIdx.x & (BB - 1);
    const int qt  = blockIdx.x >> 5;
    const int qbase = qt * QBLK + wid * 16;
    const int valid = vlen[b];

    // ---- Q A-frags in regs, pre-scaled by 1/sqrt(D) * log2(e)
    const float QSCALE = 0.125f * 1.44269504088896341f;
    bf16x8 qf[2];
    {
        const float* Qr = Q + ((size_t)b * LL + qbase + lq) * DD;
        #pragma unroll
        for (int ds_ = 0; ds_ < 2; ++ds_) {
            const float4* p4 = reinterpret_cast<const float4*>(Qr + ds_ * 32 + lg * 8);
            float4 a = p4[0], c = p4[1];
            bf16x8 f;
            f[0] = f2bf(a.x * QSCALE); f[1] = f2bf(a.y * QSCALE);
            f[2] = f2bf(a.z * QSCALE); f[3] = f2bf(a.w * QSCALE);
            f[4] = f2bf(c.x * QSCALE); f[5] = f2bf(c.y * QSCALE);
            f[6] = f2bf(c.z * QSCALE); f[7] = f2bf(c.w * QSCALE);
            qf[ds_] = f;
        }
    }

    f32x4 acc[4];
    #pragma unroll
    for (int n = 0; n < 4; ++n) acc[n] = (f32x4){0.f, 0.f, 0.f, 0.f};
    float m_[4], l_[4];
    #pragma unroll
    for (int r = 0; r < 4; ++r) { m_[r] = -1e30f; l_[r] = 0.f; }

    const int ntiles = (valid + KBLK - 1) / KBLK;
    const float4* Kg4 = reinterpret_cast<const float4*>(K + (size_t)b * LL * DD);
    const float4* Vg4 = reinterpret_cast<const float4*>(V + (size_t)b * LL * DD);

    // ---- prefetch tile 0 into regs
    float4 kpre[4], vpre[4];
    #pragma unroll
    for (int i = 0; i < 4; ++i) {
        int idx = tid + i * 256;
        kpre[i] = Kg4[idx];
        vpre[i] = Vg4[idx];
    }

    for (int kt = 0; kt < ntiles; ++kt) {
        __syncthreads();   // previous tile's LDS consumers done

        // ---- staged regs -> LDS (fp32->bf16, swizzled)
        #pragma unroll
        for (int i = 0; i < 4; ++i) {
            int idx = tid + i * 256;
            int kr  = idx >> 4;
            int dc  = (idx & 15) * 4;
            float4 kv = kpre[i];
            unsigned lo = (unsigned short)f2bf(kv.x) | ((unsigned)(unsigned short)f2bf(kv.y) << 16);
            unsigned hi = (unsigned short)f2bf(kv.z) | ((unsigned)(unsigned short)f2bf(kv.w) << 16);
            int e = (kr * 64 + dc) ^ kswz(kr);
            *reinterpret_cast<unsigned*>(&Ks[e])     = lo;
            *reinterpret_cast<unsigned*>(&Ks[e + 2]) = hi;
            float4 vv = vpre[i];
            Vt[((dc + 0) * 64 + kr) ^ vswz(dc + 0)] = f2bf(vv.x);
            Vt[((dc + 1) * 64 + kr) ^ vswz(dc + 1)] = f2bf(vv.y);
            Vt[((dc + 2) * 64 + kr) ^ vswz(dc + 2)] = f2bf(vv.z);
            Vt[((dc + 3) * 64 + kr) ^ vswz(dc + 3)] = f2bf(vv.w);
        }
        __syncthreads();

        // ---- issue next tile's loads; latency hides under compute
        if (kt + 1 < ntiles) {
            const int base4 = (kt + 1) * KBLK * (DD / 4);
            #pragma unroll
            for (int i = 0; i < 4; ++i) {
                int idx = tid + i * 256;
                kpre[i] = Kg4[base4 + idx];
                vpre[i] = Vg4[base4 + idx];
            }
        }

        // ---- QK^T (s already in log2 units via pre-scaled Q)
        f32x4 s[4];
        #pragma unroll
        for (int t = 0; t < 4; ++t) {
            f32x4 a = (f32x4){0.f, 0.f, 0.f, 0.f};
            const int krow = t * 16 + lq;
            #pragma unroll
            for (int ds_ = 0; ds_ < 2; ++ds_) {
                int e = (krow * 64 + ds_ * 32 + lg * 8) ^ kswz(krow);
                bf16x8 kf = *reinterpret_cast<const bf16x8*>(&Ks[e]);
                a = __builtin_amdgcn_mfma_f32_16x16x32_bf16(qf[ds_], kf, a, 0, 0, 0);
            }
            s[t] = a;
        }

        // ---- mask(last partial tile only) + row-max
        const bool tail = (kt == ntiles - 1) && (valid & (KBLK - 1));
        float rowmax[4];
        #pragma unroll
        for (int r = 0; r < 4; ++r) {
            float mx = -1e30f;
            #pragma unroll
            for (int t = 0; t < 4; ++t) {
                float v = s[t][r];
                if (tail) {
                    int kg = kt * KBLK + t * 16 + lq;
                    v = (kg < valid) ? v : -1e30f;
                    s[t][r] = v;
                }
                mx = fmaxf(mx, v);
            }
            #pragma unroll
            for (int off = 1; off < 16; off <<= 1)
                mx = fmaxf(mx, __shfl_xor(mx, off, 64));
            rowmax[r] = mx;
        }

        // ---- defer-max (T13): rescale only when max grew > 8 (log2 domain)
        float grow = 0.f;
        #pragma unroll
        for (int r = 0; r < 4; ++r) grow = fmaxf(grow, rowmax[r] - m_[r]);
        if (__any(grow > 8.0f)) {
            float corr[4];
            #pragma unroll
            for (int r = 0; r < 4; ++r) {
                float mnew = fmaxf(m_[r], rowmax[r]);
                corr[r] = exp2c(m_[r] - mnew);
                m_[r] = mnew;
                l_[r] *= corr[r];
            }
            #pragma unroll
            for (int n = 0; n < 4; ++n) {
                acc[n][0] *= corr[0]; acc[n][1] *= corr[1];
                acc[n][2] *= corr[2]; acc[n][3] *= corr[3];
            }
        }

        // ---- p = exp2(s - m), row-sum, P -> wave-private LDS
        short* Pw = &Pl[wid * (16 * KBLK)];
        #pragma unroll
        for (int r = 0; r < 4; ++r) {
            float ls = 0.f;
            #pragma unroll
            for (int t = 0; t < 4; ++t) {
                float p = exp2c(s[t][r] - m_[r]);
                s[t][r] = p;
                ls += p;
            }
            #pragma unroll
            for (int off = 1; off < 16; off <<= 1)
                ls += __shfl_xor(ls, off, 64);
            l_[r] += ls;
        }
        #pragma unroll
        for (int t = 0; t < 4; ++t) {
            #pragma unroll
            for (int r = 0; r < 4; ++r) {
                int qrow = lg * 4 + r;
                Pw[(qrow * 64 + t * 16 + lq) ^ kswz(qrow)] = f2bf(s[t][r]);
            }
        }

        // ---- PV
        #pragma unroll
        for (int ks_ = 0; ks_ < 2; ++ks_) {
            int pe = (lq * 64 + ks_ * 32 + lg * 8) ^ kswz(lq);
            bf16x8 pf = *reinterpret_cast<const bf16x8*>(&Pw[pe]);
            #pragma unroll
            for (int n = 0; n < 4; ++n) {
                int drow = n * 16 + lq;
                int ve = (drow * 64 + ks_ * 32 + lg * 8) ^ vswz(drow);
                bf16x8 vf = *reinterpret_cast<const bf16x8*>(&Vt[ve]);
                acc[n] = __builtin_amdgcn_mfma_f32_16x16x32_bf16(pf, vf, acc[n], 0, 0, 0);
            }
        }
    }

    // ---- epilogue
    float inv[4];
    #pragma unroll
    for (int r = 0; r < 4; ++r) inv[r] = 1.f / l_[r];
    float* Ob = O + ((size_t)b * LL + qbase) * DD;
    #pragma unroll
    for (int n = 0; n < 4; ++n) {
        #pragma unroll
        for (int r = 0; r < 4; ++r) {
            Ob[(size_t)(lg * 4 + r) * DD + n * 16 + lq] = acc[n][r] * inv[r];
        }
    }
}

extern "C" void kernel_launch(void* const* d_in, const int* in_sizes, int n_in,
                              void* d_out, int out_size, void* d_ws, size_t ws_size,
                              hipStream_t stream) {
    const float* Q = (const float*)d_in[0];
    const float* K = (const float*)d_in[1];
    const float* V = (const float*)d_in[2];
    const int* vlen = (const int*)d_in[3];
    float* O = (float*)d_out;

    dim3 grid(BB * (LL / QBLK));   // 1024 blocks, qt-major mapping
    dim3 block(256);               // 4 waves
    attn_mfma_kernel<<<grid, block, 0, stream>>>(Q, K, V, vlen, O);
}

// Round 5
// 89.495 us; speedup vs baseline: 2.5359x; 1.4328x over previous
//
#include <hip/hip_runtime.h>
#include <hip/hip_bf16.h>
#include <math.h>

// DotProductAttention B=32, L=2048, D=64, fp32 IO, per-batch key-length mask.
// Round 5: work-queue + swapped QK^T in-lane softmax + packed LDS staging.
//  - 512 persistent blocks (2/CU) pull q-tiles from atomic counter in d_ws:
//    fixes the 1.8x load-imbalance makespan (occupancy was 14.5%).
//  - QK^T computed swapped: s = mfma(K_frag, Q_frag) -> lane holds S[k][q=lq];
//    softmax row-reduce = in-lane over 16 regs + 2 shfl_xor; m/l scalars.
//  - P write: 4x ds_write_b64 (k-consecutive in-lane), was 16x b16.
//  - V staged via in-thread 4x4 transpose: 4x ds_write_b64, was 16x b16.
//  - P swizzle fixed: ((row&7)^(row>>3))<<3 (old collapsed lg groups).

#define BB 32
#define LL 2048
#define DD 64
#define QBLK 64
#define KBLK 64
#define NTILES (BB * (LL / QBLK))   // 1024
#define GRID 512

typedef __attribute__((ext_vector_type(8))) short bf16x8;
typedef __attribute__((ext_vector_type(4))) float f32x4;

static __device__ __forceinline__ short f2bf(float f) {
    __hip_bfloat16 h = __float2bfloat16(f);
    return *reinterpret_cast<short*>(&h);
}
static __device__ __forceinline__ unsigned pk2(float a, float b) {
    return (unsigned)(unsigned short)f2bf(a) | ((unsigned)(unsigned short)f2bf(b) << 16);
}
static __device__ __forceinline__ float exp2c(float x) {
    return __builtin_amdgcn_exp2f(x);
}
static __device__ __forceinline__ int kswz(int row) { return (row & 7) << 3; }
static __device__ __forceinline__ int vswz(int d)   { return ((d ^ (d >> 2)) & 7) << 3; }
static __device__ __forceinline__ int pswz(int row) { return (((row & 7) ^ (row >> 3)) & 7) << 3; }

__global__ void init_ctr_kernel(int* ctr) { *ctr = 0; }

__global__ __launch_bounds__(256, 2) void attn_mfma_kernel(
    const float* __restrict__ Q, const float* __restrict__ K,
    const float* __restrict__ V, const int* __restrict__ vlen,
    float* __restrict__ O, int* __restrict__ ctr)
{
    __shared__ __align__(16) short Ks[KBLK * DD];      // [k][d], kswz
    __shared__ __align__(16) short Vt[DD * KBLK];      // [d][k], vswz
    __shared__ __align__(16) short Pl[4 * 16 * KBLK];  // per-wave [q][k], pswz
    __shared__ int s_tile;

    const int tid  = threadIdx.x;
    const int wid  = tid >> 6;
    const int lane = tid & 63;
    const int lq   = lane & 15;
    const int lg   = lane >> 4;

    // V staging mapping: thread owns 4 k-rows x 4 d-cols
    const int vd4 = (tid & 15) * 4;     // d base
    const int vkr = (tid >> 4) * 4;     // k base

    const float QSCALE = 0.125f * 1.44269504088896341f;  // 1/sqrt(D) * log2(e)

    for (;;) {
        __syncthreads();                 // prev tile fully done before s_tile reuse
        if (tid == 0) s_tile = atomicAdd(ctr, 1);
        __syncthreads();
        const int tile = s_tile;
        if (tile >= NTILES) break;

        const int b     = tile & (BB - 1);
        const int qt    = tile >> 5;
        const int qbase = qt * QBLK + wid * 16;
        const int valid = vlen[b];

        // ---- Q B-frags (regs): lane holds Q[qbase+lq][ds*32 + lg*8 .. +7]
        bf16x8 qf[2];
        {
            const float* Qr = Q + ((size_t)b * LL + qbase + lq) * DD;
            #pragma unroll
            for (int ds_ = 0; ds_ < 2; ++ds_) {
                const float4* p4 = reinterpret_cast<const float4*>(Qr + ds_ * 32 + lg * 8);
                float4 a = p4[0], c = p4[1];
                bf16x8 f;
                f[0] = f2bf(a.x * QSCALE); f[1] = f2bf(a.y * QSCALE);
                f[2] = f2bf(a.z * QSCALE); f[3] = f2bf(a.w * QSCALE);
                f[4] = f2bf(c.x * QSCALE); f[5] = f2bf(c.y * QSCALE);
                f[6] = f2bf(c.z * QSCALE); f[7] = f2bf(c.w * QSCALE);
                qf[ds_] = f;
            }
        }

        f32x4 acc[4];                    // acc[n][r]: q=lg*4+r, d=n*16+lq
        #pragma unroll
        for (int n = 0; n < 4; ++n) acc[n] = (f32x4){0.f, 0.f, 0.f, 0.f};
        float m_ = -1e30f, l_ = 0.f;     // scalars for q = lq

        const int ntiles = (valid + KBLK - 1) / KBLK;
        const float4* Kg4 = reinterpret_cast<const float4*>(K + (size_t)b * LL * DD);
        const float4* Vg4 = reinterpret_cast<const float4*>(V + (size_t)b * LL * DD);

        // ---- prefetch k-tile 0
        float4 kpre[4], vpre[4];
        #pragma unroll
        for (int i = 0; i < 4; ++i) kpre[i] = Kg4[tid + i * 256];
        #pragma unroll
        for (int r = 0; r < 4; ++r) vpre[r] = Vg4[(vkr + r) * 16 + (tid & 15)];

        for (int kt = 0; kt < ntiles; ++kt) {
            __syncthreads();             // prev k-tile's LDS consumers done

            // ---- K regs -> LDS: 1x b64 per float4
            #pragma unroll
            for (int i = 0; i < 4; ++i) {
                int idx = tid + i * 256;
                int kr  = idx >> 4;
                int dc  = (idx & 15) * 4;
                float4 kv = kpre[i];
                int e = (kr * 64 + dc) ^ kswz(kr);
                *reinterpret_cast<uint2*>(&Ks[e]) =
                    make_uint2(pk2(kv.x, kv.y), pk2(kv.z, kv.w));
            }
            // ---- V regs -> LDS: in-thread 4x4 transpose, 4x b64
            {
                float4 v0 = vpre[0], v1 = vpre[1], v2 = vpre[2], v3 = vpre[3];
                int e0 = ((vd4 + 0) * 64 + vkr) ^ vswz(vd4 + 0);
                *reinterpret_cast<uint2*>(&Vt[e0]) = make_uint2(pk2(v0.x, v1.x), pk2(v2.x, v3.x));
                int e1 = ((vd4 + 1) * 64 + vkr) ^ vswz(vd4 + 1);
                *reinterpret_cast<uint2*>(&Vt[e1]) = make_uint2(pk2(v0.y, v1.y), pk2(v2.y, v3.y));
                int e2 = ((vd4 + 2) * 64 + vkr) ^ vswz(vd4 + 2);
                *reinterpret_cast<uint2*>(&Vt[e2]) = make_uint2(pk2(v0.z, v1.z), pk2(v2.z, v3.z));
                int e3 = ((vd4 + 3) * 64 + vkr) ^ vswz(vd4 + 3);
                *reinterpret_cast<uint2*>(&Vt[e3]) = make_uint2(pk2(v0.w, v1.w), pk2(v2.w, v3.w));
            }
            __syncthreads();

            // ---- issue next k-tile's loads; hide under compute
            if (kt + 1 < ntiles) {
                const int base4 = (kt + 1) * KBLK * (DD / 4);
                #pragma unroll
                for (int i = 0; i < 4; ++i) kpre[i] = Kg4[base4 + tid + i * 256];
                #pragma unroll
                for (int r = 0; r < 4; ++r) vpre[r] = Vg4[base4 + (vkr + r) * 16 + (tid & 15)];
            }

            // ---- swapped QK^T: s[t][r] = S[k = kt*64+t*16+lg*4+r][q = lq]
            f32x4 s[4];
            #pragma unroll
            for (int t = 0; t < 4; ++t) {
                f32x4 a = (f32x4){0.f, 0.f, 0.f, 0.f};
                const int krow = t * 16 + lq;
                #pragma unroll
                for (int ds_ = 0; ds_ < 2; ++ds_) {
                    int e = (krow * 64 + ds_ * 32 + lg * 8) ^ kswz(krow);
                    bf16x8 kf = *reinterpret_cast<const bf16x8*>(&Ks[e]);
                    a = __builtin_amdgcn_mfma_f32_16x16x32_bf16(kf, qf[ds_], a, 0, 0, 0);
                }
                s[t] = a;
            }

            // ---- mask (last partial tile only), in-lane row-max + 2 shfl
            const bool tail = (kt == ntiles - 1) && (valid & (KBLK - 1));
            if (tail) {
                #pragma unroll
                for (int t = 0; t < 4; ++t)
                    #pragma unroll
                    for (int r = 0; r < 4; ++r) {
                        int kg = kt * KBLK + t * 16 + lg * 4 + r;
                        if (kg >= valid) s[t][r] = -1e30f;
                    }
            }
            float mx = s[0][0];
            #pragma unroll
            for (int t = 0; t < 4; ++t)
                #pragma unroll
                for (int r = 0; r < 4; ++r) mx = fmaxf(mx, s[t][r]);
            mx = fmaxf(mx, __shfl_xor(mx, 16, 64));
            mx = fmaxf(mx, __shfl_xor(mx, 32, 64));

            // ---- defer-max (T13, log2 domain THR=8)
            if (__any(mx - m_ > 8.0f)) {
                float mnew = fmaxf(m_, mx);
                float corr = exp2c(m_ - mnew);
                m_ = mnew;
                l_ *= corr;
                #pragma unroll
                for (int r = 0; r < 4; ++r) {
                    float cq = __shfl(corr, lg * 4 + r, 64);   // corr for q=lg*4+r
                    #pragma unroll
                    for (int n = 0; n < 4; ++n) acc[n][r] *= cq;
                }
            }

            // ---- p = exp2(s - m), in-lane sum + 2 shfl, P -> LDS (4x b64)
            float ls = 0.f;
            #pragma unroll
            for (int t = 0; t < 4; ++t)
                #pragma unroll
                for (int r = 0; r < 4; ++r) {
                    float p = exp2c(s[t][r] - m_);
                    s[t][r] = p;
                    ls += p;
                }
            ls += __shfl_xor(ls, 16, 64);
            ls += __shfl_xor(ls, 32, 64);
            l_ += ls;

            short* Pw = &Pl[wid * (16 * KBLK)];
            #pragma unroll
            for (int t = 0; t < 4; ++t) {
                int e = (lq * 64 + t * 16 + lg * 4) ^ pswz(lq);
                *reinterpret_cast<uint2*>(&Pw[e]) =
                    make_uint2(pk2(s[t][0], s[t][1]), pk2(s[t][2], s[t][3]));
            }

            // ---- PV: acc[n] += P(16xK) * V(Kx16), per 32-k chunk
            #pragma unroll
            for (int ks_ = 0; ks_ < 2; ++ks_) {
                int pe = (lq * 64 + ks_ * 32 + lg * 8) ^ pswz(lq);
                bf16x8 pf = *reinterpret_cast<const bf16x8*>(&Pw[pe]);
                #pragma unroll
                for (int n = 0; n < 4; ++n) {
                    int drow = n * 16 + lq;
                    int ve = (drow * 64 + ks_ * 32 + lg * 8) ^ vswz(drow);
                    bf16x8 vf = *reinterpret_cast<const bf16x8*>(&Vt[ve]);
                    acc[n] = __builtin_amdgcn_mfma_f32_16x16x32_bf16(pf, vf, acc[n], 0, 0, 0);
                }
            }
        }

        // ---- epilogue: fetch l for q=lg*4+r via shfl, write O
        float linv[4];
        #pragma unroll
        for (int r = 0; r < 4; ++r)
            linv[r] = 1.f / __shfl(l_, lg * 4 + r, 64);
        float* Ob = O + ((size_t)b * LL + qbase) * DD;
        #pragma unroll
        for (int n = 0; n < 4; ++n) {
            #pragma unroll
            for (int r = 0; r < 4; ++r) {
                Ob[(size_t)(lg * 4 + r) * DD + n * 16 + lq] = acc[n][r] * linv[r];
            }
        }
    }
}

extern "C" void kernel_launch(void* const* d_in, const int* in_sizes, int n_in,
                              void* d_out, int out_size, void* d_ws, size_t ws_size,
                              hipStream_t stream) {
    const float* Q = (const float*)d_in[0];
    const float* K = (const float*)d_in[1];
    const float* V = (const float*)d_in[2];
    const int* vlen = (const int*)d_in[3];
    float* O = (float*)d_out;
    int* ctr = (int*)d_ws;

    init_ctr_kernel<<<1, 1, 0, stream>>>(ctr);
    attn_mfma_kernel<<<GRID, 256, 0, stream>>>(Q, K, V, vlen, O, ctr);
}

// Round 6
// 71.850 us; speedup vs baseline: 3.1586x; 1.2456x over previous
//
#include <hip/hip_runtime.h>
#include <hip/hip_bf16.h>
#include <math.h>

// DotProductAttention B=32, L=2048, D=64, fp32 IO, per-batch key-length mask.
// Round 6: LPT work queue (longest batches first) + GRID 512->768.
//  - init kernel ranks batches by valid_len desc (32-thread rank-by-count);
//    queue ticket t -> batch order[t>>5], qt = t&31. Long jobs dispensed
//    first => tail jobs are short => slack can shrink.
//  - GRID 768 = 3 blocks/CU = 12 waves/CU (was 8): more latency hiding.
//  - LPT also concentrates concurrent work on few batches -> K/V working
//    set fits per-XCD L2 (was 190MB L2-miss traffic from batch scatter).
//  - Core per-tile code identical to round 5 (swapped QK^T, in-lane
//    softmax, packed b64 staging, defer-max).

#define BB 32
#define LL 2048
#define DD 64
#define QBLK 64
#define KBLK 64
#define NTILES (BB * (LL / QBLK))   // 1024
#define GRID 768

typedef __attribute__((ext_vector_type(8))) short bf16x8;
typedef __attribute__((ext_vector_type(4))) float f32x4;

static __device__ __forceinline__ short f2bf(float f) {
    __hip_bfloat16 h = __float2bfloat16(f);
    return *reinterpret_cast<short*>(&h);
}
static __device__ __forceinline__ unsigned pk2(float a, float b) {
    return (unsigned)(unsigned short)f2bf(a) | ((unsigned)(unsigned short)f2bf(b) << 16);
}
static __device__ __forceinline__ float exp2c(float x) {
    return __builtin_amdgcn_exp2f(x);
}
static __device__ __forceinline__ int kswz(int row) { return (row & 7) << 3; }
static __device__ __forceinline__ int vswz(int d)   { return ((d ^ (d >> 2)) & 7) << 3; }
static __device__ __forceinline__ int pswz(int row) { return (((row & 7) ^ (row >> 3)) & 7) << 3; }

// ws[0] = queue counter; ws[1..32] = batch ids sorted by valid_len desc
__global__ void init_ctr_kernel(const int* __restrict__ vlen, int* __restrict__ ws) {
    int t = threadIdx.x;
    if (t == 0) ws[0] = 0;
    if (t < BB) {
        int v = vlen[t];
        int rank = 0;
        for (int j = 0; j < BB; ++j) {
            int vj = vlen[j];
            rank += (vj > v) || (vj == v && j < t);
        }
        ws[1 + rank] = t;
    }
}

__global__ __launch_bounds__(256, 2) void attn_mfma_kernel(
    const float* __restrict__ Q, const float* __restrict__ K,
    const float* __restrict__ V, const int* __restrict__ vlen,
    float* __restrict__ O, int* __restrict__ ws)
{
    __shared__ __align__(16) short Ks[KBLK * DD];      // [k][d], kswz
    __shared__ __align__(16) short Vt[DD * KBLK];      // [d][k], vswz
    __shared__ __align__(16) short Pl[4 * 16 * KBLK];  // per-wave [q][k], pswz
    __shared__ int s_tile;

    int* ctr = ws;
    const int* order = ws + 1;

    const int tid  = threadIdx.x;
    const int wid  = tid >> 6;
    const int lane = tid & 63;
    const int lq   = lane & 15;
    const int lg   = lane >> 4;

    // V staging mapping: thread owns 4 k-rows x 4 d-cols
    const int vd4 = (tid & 15) * 4;     // d base
    const int vkr = (tid >> 4) * 4;     // k base

    const float QSCALE = 0.125f * 1.44269504088896341f;  // 1/sqrt(D) * log2(e)

    for (;;) {
        __syncthreads();                 // prev tile fully done before s_tile reuse
        if (tid == 0) s_tile = atomicAdd(ctr, 1);
        __syncthreads();
        const int tile = s_tile;
        if (tile >= NTILES) break;

        const int b     = order[tile >> 5];   // LPT: longest batches first
        const int qt    = tile & 31;
        const int qbase = qt * QBLK + wid * 16;
        const int valid = vlen[b];

        // ---- Q B-frags (regs): lane holds Q[qbase+lq][ds*32 + lg*8 .. +7]
        bf16x8 qf[2];
        {
            const float* Qr = Q + ((size_t)b * LL + qbase + lq) * DD;
            #pragma unroll
            for (int ds_ = 0; ds_ < 2; ++ds_) {
                const float4* p4 = reinterpret_cast<const float4*>(Qr + ds_ * 32 + lg * 8);
                float4 a = p4[0], c = p4[1];
                bf16x8 f;
                f[0] = f2bf(a.x * QSCALE); f[1] = f2bf(a.y * QSCALE);
                f[2] = f2bf(a.z * QSCALE); f[3] = f2bf(a.w * QSCALE);
                f[4] = f2bf(c.x * QSCALE); f[5] = f2bf(c.y * QSCALE);
                f[6] = f2bf(c.z * QSCALE); f[7] = f2bf(c.w * QSCALE);
                qf[ds_] = f;
            }
        }

        f32x4 acc[4];                    // acc[n][r]: q=lg*4+r, d=n*16+lq
        #pragma unroll
        for (int n = 0; n < 4; ++n) acc[n] = (f32x4){0.f, 0.f, 0.f, 0.f};
        float m_ = -1e30f, l_ = 0.f;     // scalars for q = lq (k-major lanes)

        const int ntiles = (valid + KBLK - 1) / KBLK;
        const float4* Kg4 = reinterpret_cast<const float4*>(K + (size_t)b * LL * DD);
        const float4* Vg4 = reinterpret_cast<const float4*>(V + (size_t)b * LL * DD);

        // ---- prefetch k-tile 0
        float4 kpre[4], vpre[4];
        #pragma unroll
        for (int i = 0; i < 4; ++i) kpre[i] = Kg4[tid + i * 256];
        #pragma unroll
        for (int r = 0; r < 4; ++r) vpre[r] = Vg4[(vkr + r) * 16 + (tid & 15)];

        for (int kt = 0; kt < ntiles; ++kt) {
            __syncthreads();             // prev k-tile's LDS consumers done

            // ---- K regs -> LDS: 1x b64 per float4
            #pragma unroll
            for (int i = 0; i < 4; ++i) {
                int idx = tid + i * 256;
                int kr  = idx >> 4;
                int dc  = (idx & 15) * 4;
                float4 kv = kpre[i];
                int e = (kr * 64 + dc) ^ kswz(kr);
                *reinterpret_cast<uint2*>(&Ks[e]) =
                    make_uint2(pk2(kv.x, kv.y), pk2(kv.z, kv.w));
            }
            // ---- V regs -> LDS: in-thread 4x4 transpose, 4x b64
            {
                float4 v0 = vpre[0], v1 = vpre[1], v2 = vpre[2], v3 = vpre[3];
                int e0 = ((vd4 + 0) * 64 + vkr) ^ vswz(vd4 + 0);
                *reinterpret_cast<uint2*>(&Vt[e0]) = make_uint2(pk2(v0.x, v1.x), pk2(v2.x, v3.x));
                int e1 = ((vd4 + 1) * 64 + vkr) ^ vswz(vd4 + 1);
                *reinterpret_cast<uint2*>(&Vt[e1]) = make_uint2(pk2(v0.y, v1.y), pk2(v2.y, v3.y));
                int e2 = ((vd4 + 2) * 64 + vkr) ^ vswz(vd4 + 2);
                *reinterpret_cast<uint2*>(&Vt[e2]) = make_uint2(pk2(v0.z, v1.z), pk2(v2.z, v3.z));
                int e3 = ((vd4 + 3) * 64 + vkr) ^ vswz(vd4 + 3);
                *reinterpret_cast<uint2*>(&Vt[e3]) = make_uint2(pk2(v0.w, v1.w), pk2(v2.w, v3.w));
            }
            __syncthreads();

            // ---- issue next k-tile's loads; hide under compute
            if (kt + 1 < ntiles) {
                const int base4 = (kt + 1) * KBLK * (DD / 4);
                #pragma unroll
                for (int i = 0; i < 4; ++i) kpre[i] = Kg4[base4 + tid + i * 256];
                #pragma unroll
                for (int r = 0; r < 4; ++r) vpre[r] = Vg4[base4 + (vkr + r) * 16 + (tid & 15)];
            }

            // ---- swapped QK^T: s[t][r] = S[k = kt*64+t*16+lg*4+r][q = lq]
            f32x4 s[4];
            #pragma unroll
            for (int t = 0; t < 4; ++t) {
                f32x4 a = (f32x4){0.f, 0.f, 0.f, 0.f};
                const int krow = t * 16 + lq;
                #pragma unroll
                for (int ds_ = 0; ds_ < 2; ++ds_) {
                    int e = (krow * 64 + ds_ * 32 + lg * 8) ^ kswz(krow);
                    bf16x8 kf = *reinterpret_cast<const bf16x8*>(&Ks[e]);
                    a = __builtin_amdgcn_mfma_f32_16x16x32_bf16(kf, qf[ds_], a, 0, 0, 0);
                }
                s[t] = a;
            }

            // ---- mask (last partial tile only), in-lane row-max + 2 shfl
            const bool tail = (kt == ntiles - 1) && (valid & (KBLK - 1));
            if (tail) {
                #pragma unroll
                for (int t = 0; t < 4; ++t)
                    #pragma unroll
                    for (int r = 0; r < 4; ++r) {
                        int kg = kt * KBLK + t * 16 + lg * 4 + r;
                        if (kg >= valid) s[t][r] = -1e30f;
                    }
            }
            float mx = s[0][0];
            #pragma unroll
            for (int t = 0; t < 4; ++t)
                #pragma unroll
                for (int r = 0; r < 4; ++r) mx = fmaxf(mx, s[t][r]);
            mx = fmaxf(mx, __shfl_xor(mx, 16, 64));
            mx = fmaxf(mx, __shfl_xor(mx, 32, 64));

            // ---- defer-max (T13, log2 domain THR=8)
            if (__any(mx - m_ > 8.0f)) {
                float mnew = fmaxf(m_, mx);
                float corr = exp2c(m_ - mnew);
                m_ = mnew;
                l_ *= corr;
                #pragma unroll
                for (int r = 0; r < 4; ++r) {
                    float cq = __shfl(corr, lg * 4 + r, 64);   // corr for q=lg*4+r
                    #pragma unroll
                    for (int n = 0; n < 4; ++n) acc[n][r] *= cq;
                }
            }

            // ---- p = exp2(s - m), in-lane sum + 2 shfl, P -> LDS (4x b64)
            float ls = 0.f;
            #pragma unroll
            for (int t = 0; t < 4; ++t)
                #pragma unroll
                for (int r = 0; r < 4; ++r) {
                    float p = exp2c(s[t][r] - m_);
                    s[t][r] = p;
                    ls += p;
                }
            ls += __shfl_xor(ls, 16, 64);
            ls += __shfl_xor(ls, 32, 64);
            l_ += ls;

            short* Pw = &Pl[wid * (16 * KBLK)];
            #pragma unroll
            for (int t = 0; t < 4; ++t) {
                int e = (lq * 64 + t * 16 + lg * 4) ^ pswz(lq);
                *reinterpret_cast<uint2*>(&Pw[e]) =
                    make_uint2(pk2(s[t][0], s[t][1]), pk2(s[t][2], s[t][3]));
            }

            // ---- PV: acc[n] += P(16xK) * V(Kx16), per 32-k chunk
            #pragma unroll
            for (int ks_ = 0; ks_ < 2; ++ks_) {
                int pe = (lq * 64 + ks_ * 32 + lg * 8) ^ pswz(lq);
                bf16x8 pf = *reinterpret_cast<const bf16x8*>(&Pw[pe]);
                #pragma unroll
                for (int n = 0; n < 4; ++n) {
                    int drow = n * 16 + lq;
                    int ve = (drow * 64 + ks_ * 32 + lg * 8) ^ vswz(drow);
                    bf16x8 vf = *reinterpret_cast<const bf16x8*>(&Vt[ve]);
                    acc[n] = __builtin_amdgcn_mfma_f32_16x16x32_bf16(pf, vf, acc[n], 0, 0, 0);
                }
            }
        }

        // ---- epilogue: fetch l for q=lg*4+r via shfl, write O
        float linv[4];
        #pragma unroll
        for (int r = 0; r < 4; ++r)
            linv[r] = 1.f / __shfl(l_, lg * 4 + r, 64);
        float* Ob = O + ((size_t)b * LL + qbase) * DD;
        #pragma unroll
        for (int n = 0; n < 4; ++n) {
            #pragma unroll
            for (int r = 0; r < 4; ++r) {
                Ob[(size_t)(lg * 4 + r) * DD + n * 16 + lq] = acc[n][r] * linv[r];
            }
        }
    }
}

extern "C" void kernel_launch(void* const* d_in, const int* in_sizes, int n_in,
                              void* d_out, int out_size, void* d_ws, size_t ws_size,
                              hipStream_t stream) {
    const float* Q = (const float*)d_in[0];
    const float* K = (const float*)d_in[1];
    const float* V = (const float*)d_in[2];
    const int* vlen = (const int*)d_in[3];
    float* O = (float*)d_out;
    int* ws = (int*)d_ws;

    init_ctr_kernel<<<1, 64, 0, stream>>>(vlen, ws);
    attn_mfma_kernel<<<GRID, 256, 0, stream>>>(Q, K, V, vlen, O, ws);
}